// Round 5
// baseline (354.350 us; speedup 1.0000x reference)
//
#include <hip/hip_runtime.h>
#include <hip/hip_bf16.h>
#include <cstddef>

// ---------------------------------------------------------------------------
// GCN 2-layer forward.
//  h1 = relu(Agg(x @ W1) + b1);  out = log_softmax(Agg(h1 @ W2) + b2)
//  Agg(z)[i] = dinv[i] * ( t[i] + sum_e w_e t[src_e] ),  t = dinv * (z @ W)
// Round 5: feature-sliced aggregation. Gather tables stored slice-major
// [slice][n][32] (3.2 MB bf16 per slice < 4 MB per-XCD L2); aggregation runs
// as sequential per-slice passes so the active slice stays L2-resident
// (round-4 profile: 37% steady-state miss rate on the 12.8 MB table was the
// latency limiter; MLP was already capped). 8 lanes/edge, 16 edges in flight.
// ---------------------------------------------------------------------------

#define DIN 256
#define DH  128
#define DOUT 64
#define NPB 100        // nodes per bucket (50000/100 = 500 buckets)
#define NBMAX 512      // max buckets (shared-array size)

typedef __bf16 bf16x8 __attribute__((ext_vector_type(8)));
typedef float f32x4 __attribute__((ext_vector_type(4)));

__device__ __forceinline__ float bflo(unsigned u) { return __uint_as_float(u << 16); }
__device__ __forceinline__ float bfhi(unsigned u) { return __uint_as_float(u & 0xffff0000u); }
__device__ __forceinline__ unsigned short f2bf(float f) {
    unsigned u = __float_as_uint(f);
    unsigned r = (u + 0x7fffu + ((u >> 16) & 1u)) >> 16;   // round-nearest-even
    return (unsigned short)r;
}

// Convert + transpose weights once: wt[n][k] = bf16(W[k][n]).
__global__ void prep_w_kernel(const float* __restrict__ W1, const float* __restrict__ W2,
                              unsigned short* __restrict__ wt1, unsigned short* __restrict__ wt2) {
    int i = blockIdx.x * 256 + threadIdx.x;
    if (i < DH * DIN) {                       // wt1 [128][256]
        int nn = i >> 8, k = i & 255;
        wt1[i] = f2bf(W1[k * DH + nn]);
    } else {
        int j = i - DH * DIN;
        if (j < DOUT * DH) {                  // wt2 [64][128]
            int nn = j >> 7, k = j & 127;
            wt2[j] = f2bf(W2[k * DOUT + nn]);
        }
    }
}

// Pass 1: per-block bucket histogram (LDS), write bh[p][NB].
__launch_bounds__(256)
__global__ void hist_kernel(const int* __restrict__ col, int* __restrict__ bh,
                            int E, int Ec, int NB) {
    __shared__ int hist[NBMAX];
    int p = blockIdx.x, t = threadIdx.x;
    for (int b = t; b < NB; b += 256) hist[b] = 0;
    __syncthreads();
    int s = p * Ec, e = min(s + Ec, E);
    for (int i = s + t; i < e; i += 256) atomicAdd(&hist[col[i] / NPB], 1);
    __syncthreads();
    for (int b = t; b < NB; b += 256) bh[p * NB + b] = hist[b];
}

// Pass 2: per-bucket column scan over blocks (exclusive, in place).
__launch_bounds__(512)
__global__ void colscan_kernel(int* __restrict__ bh, int* __restrict__ btotal,
                               int P, int NB) {
    __shared__ int arr[512];
    int b = blockIdx.x, t = threadIdx.x;
    arr[t] = (t < P) ? bh[t * NB + b] : 0;
    __syncthreads();
    for (int off = 1; off < 512; off <<= 1) {
        int v = (t >= off) ? arr[t - off] : 0;
        __syncthreads();
        arr[t] += v;
        __syncthreads();
    }
    int excl = (t == 0) ? 0 : arr[t - 1];
    if (t < P) bh[t * NB + b] = excl;
    if (t == P - 1) btotal[b] = arr[t];
}

// Pass 2b: exclusive scan of btotal -> bbase[0..NB]; rowptr[n]=E.
__launch_bounds__(512)
__global__ void basescan_kernel(const int* __restrict__ btotal, int* __restrict__ bbase,
                                int* __restrict__ rowptr, int NB, int n, int E) {
    __shared__ int arr[512];
    int t = threadIdx.x;
    arr[t] = (t < NB) ? btotal[t] : 0;
    __syncthreads();
    for (int off = 1; off < 512; off <<= 1) {
        int v = (t >= off) ? arr[t - off] : 0;
        __syncthreads();
        arr[t] += v;
        __syncthreads();
    }
    int excl = (t == 0) ? 0 : arr[t - 1];
    if (t <= NB) bbase[t] = excl;
    if (t == 511) rowptr[n] = E;
}

// Pass 3: scatter edges into bucket-partitioned order via LDS cursors.
// part[pos] = (row | col_local<<16, w_bits).
__launch_bounds__(256)
__global__ void scatter_kernel(const int* __restrict__ row, const int* __restrict__ col,
                               const float* __restrict__ w, const int* __restrict__ bh,
                               const int* __restrict__ bbase, int2* __restrict__ part,
                               int E, int Ec, int NB) {
    __shared__ int cur[NBMAX];
    int p = blockIdx.x, t = threadIdx.x;
    for (int b = t; b < NB; b += 256) cur[b] = bbase[b] + bh[p * NB + b];
    __syncthreads();
    int s = p * Ec, e = min(s + Ec, E);
    for (int i = s + t; i < e; i += 256) {
        int c = col[i];
        int r = row[i];
        int b = c / NPB;
        int pos = atomicAdd(&cur[b], 1);          // LDS atomic
        part[pos] = make_int2(r | ((c - b * NPB) << 16), __float_as_int(w[i]));
    }
}

// Pass 4: one block per bucket: per-node deg/dinv/rowptr + per-node CSR.
__launch_bounds__(256)
__global__ void bucket_csr_kernel(const int2* __restrict__ part, const int* __restrict__ bbase,
                                  float* __restrict__ dinv, int* __restrict__ rowptr,
                                  int2* __restrict__ final_e, int n) {
    __shared__ int   hist[NPB];
    __shared__ float wsum[NPB];
    __shared__ int   nbase[NPB];
    __shared__ int   cur[NPB];
    int b = blockIdx.x, t = threadIdx.x;
    if (t < NPB) { hist[t] = 0; wsum[t] = 0.0f; }
    __syncthreads();
    int s = bbase[b], e = bbase[b + 1];
    for (int i = s + t; i < e; i += 256) {
        int2 rec = part[i];
        int cl = rec.x >> 16;
        atomicAdd(&hist[cl], 1);
        atomicAdd(&wsum[cl], __int_as_float(rec.y));
    }
    __syncthreads();
    if (t == 0) {
        int run = 0;
        for (int k = 0; k < NPB; ++k) { nbase[k] = run; run += hist[k]; }
    }
    __syncthreads();
    if (t < NPB) {
        int node = b * NPB + t;
        if (node < n) {
            dinv[node] = rsqrtf(1.0f + wsum[t]);   // deg >= 1 (self-loop)
            rowptr[node] = s + nbase[t];
        }
        cur[t] = nbase[t];
    }
    __syncthreads();
    for (int i = s + t; i < e; i += 256) {
        int2 rec = part[i];
        int cl = rec.x >> 16;
        int q = s + atomicAdd(&cur[cl], 1);       // LDS atomic
        final_e[q] = make_int2(rec.x & 0xffff, rec.y);   // (src, raw w); n < 65536
    }
}

// MFMA GEMM: C_slice[s][r][f] = bf16( scale[r] * (A[r][:K] @ B)[s*32+f] ),
// B transposed bf16 Wt[M][K]. ASLICED: A stored [K/32][N][32] fp32.
// Block: 64 rows x full M, 4 waves.
template <int K, int M, bool ASLICED>
__launch_bounds__(256)
__global__ void gemm_mfma_kernel(const float* __restrict__ A,
                                 const unsigned short* __restrict__ Wt,
                                 const float* __restrict__ scale,
                                 unsigned short* __restrict__ C, int N) {
    constexpr int BK = 64, LD = BK + 8;
    constexpr int WN = M / 4;
    constexpr int NT = WN / 16;
    constexpr int CLD = M + 8;
    constexpr int SM = (64 * LD + M * LD) > (64 * CLD) ? (64 * LD + M * LD) : (64 * CLD);
    __shared__ unsigned short smem[SM];
    __shared__ float sdv[64];
    unsigned short* As = smem;                // [64][LD]
    unsigned short* Bs = smem + 64 * LD;      // [M][LD]

    const int tid = threadIdx.x;
    const int row0 = blockIdx.x * 64;
    const int lane = tid & 63;
    const int quad = lane >> 4, r16 = lane & 15;
    const int n0 = (tid >> 6) * WN;

    if (tid < 64) {
        int r = row0 + tid;
        sdv[tid] = (r < N) ? scale[r] : 0.0f;
    }

    f32x4 acc[4][NT];
#pragma unroll
    for (int mt = 0; mt < 4; ++mt)
#pragma unroll
        for (int nt = 0; nt < NT; ++nt)
            acc[mt][nt] = (f32x4){0.f, 0.f, 0.f, 0.f};

    for (int k0 = 0; k0 < K; k0 += BK) {
        // stage A: 64 rows x 64 k, fp32 -> bf16
#pragma unroll
        for (int j = 0; j < 4; ++j) {
            int idx = tid + j * 256;
            int m = idx >> 4;
            int q = idx & 15;
            int gr = row0 + m;
            int k = k0 + q * 4;
            float4 v = make_float4(0.f, 0.f, 0.f, 0.f);
            if (gr < N) {
                if (ASLICED)
                    v = *(const float4*)&A[((size_t)(k >> 5) * N + gr) * 32 + (k & 31)];
                else
                    v = *(const float4*)&A[(size_t)gr * K + k];
            }
            ushort4 s4;
            s4.x = f2bf(v.x); s4.y = f2bf(v.y); s4.z = f2bf(v.z); s4.w = f2bf(v.w);
            *(ushort4*)&As[m * LD + q * 4] = s4;
        }
        // stage B: M rows(n) x 64 k bf16
#pragma unroll
        for (int j = 0; j < M * 8 / 256; ++j) {
            int idx = tid + j * 256;
            int nn = idx >> 3;
            int q = idx & 7;
            uint4 v = *(const uint4*)&Wt[(size_t)nn * K + k0 + q * 8];
            *(uint4*)&Bs[nn * LD + q * 8] = v;
        }
        __syncthreads();
#pragma unroll
        for (int ks = 0; ks < BK / 32; ++ks) {
            bf16x8 af[4], bfr[NT];
#pragma unroll
            for (int nt = 0; nt < NT; ++nt)
                bfr[nt] = *(const bf16x8*)&Bs[(n0 + nt * 16 + r16) * LD + ks * 32 + quad * 8];
#pragma unroll
            for (int mt = 0; mt < 4; ++mt)
                af[mt] = *(const bf16x8*)&As[(mt * 16 + r16) * LD + ks * 32 + quad * 8];
#pragma unroll
            for (int mt = 0; mt < 4; ++mt)
#pragma unroll
                for (int nt = 0; nt < NT; ++nt)
                    acc[mt][nt] = __builtin_amdgcn_mfma_f32_16x16x32_bf16(
                        af[mt], bfr[nt], acc[mt][nt], 0, 0, 0);
        }
        __syncthreads();
    }
    // epilogue: scale, bf16, LDS stage, slice-major store [M/32][N][32]
    unsigned short* Cs = smem;                // [64][CLD]
#pragma unroll
    for (int mt = 0; mt < 4; ++mt) {
#pragma unroll
        for (int i = 0; i < 4; ++i) {
            int r = mt * 16 + quad * 4 + i;
            float sc = sdv[r];
#pragma unroll
            for (int nt = 0; nt < NT; ++nt)
                Cs[r * CLD + n0 + nt * 16 + r16] = f2bf(acc[mt][nt][i] * sc);
        }
    }
    __syncthreads();
#pragma unroll
    for (int j = 0; j < 64 * M / 8 / 256; ++j) {
        int idx = tid + j * 256;
        int r = idx / (M / 8);
        int q = idx % (M / 8);
        int gr = row0 + r;
        if (gr < N) {
            uint4 v = *(const uint4*)&Cs[r * CLD + q * 8];
            *(uint4*)&C[((size_t)(q >> 2) * N + gr) * 32 + (q & 3) * 8] = v;
        }
    }
}

// One aggregation pass over a 32-feature slice.
// Wave = 1 node; lane = (slot 0..7, fq 0..7): slot picks the edge, fq picks
// the 4-feature group. 2 gather instructions (16 edges) in flight per iter.
// tbl: bf16 slice [n][32] (pre-scaled by dinv); outs: fp32 slice [n][32].
template <bool RELU>
__launch_bounds__(256)
__global__ void agg_pass_kernel(const unsigned short* __restrict__ tbl,
                                const int* __restrict__ rowptr,
                                const int2* __restrict__ edge,     // (src, raw w)
                                const float* __restrict__ dinv,
                                const float* __restrict__ bias,    // fp32 [32] slice
                                float* __restrict__ outs, int n) {
    int node = blockIdx.x * 4 + (threadIdx.x >> 6);
    if (node >= n) return;
    const int lane = threadIdx.x & 63;
    const int slot = lane >> 3;
    const int fq = lane & 7;
    const uint2* t = (const uint2*)tbl;       // [n][8] uint2 (4 bf16 each)

    float a0 = 0.f, a1 = 0.f, a2 = 0.f, a3 = 0.f;
    if (slot == 0) {                          // self term, weight 1
        uint2 u = t[(size_t)node * 8 + fq];
        a0 = bflo(u.x); a1 = bfhi(u.x); a2 = bflo(u.y); a3 = bfhi(u.y);
    }
    int p0 = rowptr[node], p1 = rowptr[node + 1];
    for (int p = p0; p < p1; p += 16) {
        int i0 = p + slot, i1 = p + 8 + slot;
        bool v0 = i0 < p1, v1 = i1 < p1;
        int2 e0 = edge[v0 ? i0 : p0];
        int2 e1 = edge[v1 ? i1 : p0];
        float w0 = v0 ? __int_as_float(e0.y) : 0.0f;
        float w1 = v1 ? __int_as_float(e1.y) : 0.0f;
        uint2 g0 = t[(size_t)e0.x * 8 + fq];
        uint2 g1 = t[(size_t)e1.x * 8 + fq];
        a0 += w0 * bflo(g0.x) + w1 * bflo(g1.x);
        a1 += w0 * bfhi(g0.x) + w1 * bfhi(g1.x);
        a2 += w0 * bflo(g0.y) + w1 * bflo(g1.y);
        a3 += w0 * bfhi(g0.y) + w1 * bfhi(g1.y);
    }
    // reduce across the 8 edge slots (lane bits 3..5)
#pragma unroll
    for (int off = 8; off <= 32; off <<= 1) {
        a0 += __shfl_xor(a0, off); a1 += __shfl_xor(a1, off);
        a2 += __shfl_xor(a2, off); a3 += __shfl_xor(a3, off);
    }
    float di = dinv[node];
    float4 b = ((const float4*)bias)[fq];
    a0 = di * a0 + b.x; a1 = di * a1 + b.y;
    a2 = di * a2 + b.z; a3 = di * a3 + b.w;
    if (RELU) {
        a0 = fmaxf(a0, 0.f); a1 = fmaxf(a1, 0.f);
        a2 = fmaxf(a2, 0.f); a3 = fmaxf(a3, 0.f);
    }
    if (slot == 0)
        ((float4*)outs)[(size_t)node * 8 + fq] = make_float4(a0, a1, a2, a3);
}

// Final log_softmax over 64 logits stored sliced lg[2][n][32] fp32.
__launch_bounds__(256)
__global__ void lsm_kernel(const float* __restrict__ lg, float* __restrict__ out, int n) {
    int node = blockIdx.x * 4 + (threadIdx.x >> 6);
    if (node >= n) return;
    int lane = threadIdx.x & 63;
    float v = lg[((size_t)(lane >> 5) * n + node) * 32 + (lane & 31)];
    float m = v;
#pragma unroll
    for (int off = 32; off > 0; off >>= 1) m = fmaxf(m, __shfl_xor(m, off));
    float s = __expf(v - m);
#pragma unroll
    for (int off = 32; off > 0; off >>= 1) s += __shfl_xor(s, off);
    out[(size_t)node * 64 + lane] = v - m - __logf(s);
}

extern "C" void kernel_launch(void* const* d_in, const int* in_sizes, int n_in,
                              void* d_out, int out_size, void* d_ws, size_t ws_size,
                              hipStream_t stream) {
    const float* x  = (const float*)d_in[0];
    const int*   ei = (const int*)d_in[1];
    const float* ew = (const float*)d_in[2];
    const float* W1 = (const float*)d_in[3];
    const float* b1 = (const float*)d_in[4];
    const float* W2 = (const float*)d_in[5];
    const float* b2 = (const float*)d_in[6];
    float* out = (float*)d_out;

    const int n = in_sizes[0] / DIN;      // 50000
    const int E = in_sizes[2];            // 1600000
    const int* row = ei;                  // edge_index[0] (source)
    const int* col = ei + E;              // edge_index[1] (target)

    const int NB = (n + NPB - 1) / NPB;   // 500 buckets
    const int P  = NB;
    const int Ec = (E + P - 1) / P;       // 3200 edges/block

    char* ptr = (char*)d_ws;
    auto alloc = [&](size_t bytes) -> void* {
        void* r = (void*)ptr;
        ptr += (bytes + 255) & ~(size_t)255;
        return r;
    };
    int*   bh     = (int*)  alloc((size_t)P * NB * 4);       // 1 MB
    int*   btotal = (int*)  alloc((size_t)NB * 4);
    int*   bbase  = (int*)  alloc((size_t)(NB + 1) * 4);
    int*   rowptr = (int*)  alloc((size_t)(n + 1) * 4);
    float* dinv   = (float*)alloc((size_t)n * 4);
    int2*  edge   = (int2*) alloc((size_t)E * 8);            // CSR edges (src, raw w)
    unsigned short* xw1 = (unsigned short*)alloc((size_t)n * DH * 2);  // bf16 sliced [4][n][32]
    unsigned short* wt1 = (unsigned short*)alloc((size_t)DH * DIN * 2);
    unsigned short* wt2 = (unsigned short*)alloc((size_t)DOUT * DH * 2);
    // tail: part (12.8MB, build) -> h1 sliced [4][n][32] fp32 (25.6MB) -> lg [2][n][32]
    char* tail = (char*)alloc((size_t)n * DH * 4);
    int2*  part = (int2*)tail;
    float* h1   = (float*)tail;
    float* lg   = (float*)tail;
    unsigned short* xw2 = xw1;            // layer-2 table aliases layer-1 table

    const int nb_g = (n + 63) / 64;       // 782
    const int nb_a = (n + 3) / 4;         // 12500

    prep_w_kernel<<<(DH * DIN + DOUT * DH + 255) / 256, 256, 0, stream>>>(W1, W2, wt1, wt2);
    hist_kernel<<<P, 256, 0, stream>>>(col, bh, E, Ec, NB);
    colscan_kernel<<<NB, 512, 0, stream>>>(bh, btotal, P, NB);
    basescan_kernel<<<1, 512, 0, stream>>>(btotal, bbase, rowptr, NB, n, E);
    scatter_kernel<<<P, 256, 0, stream>>>(row, col, ew, bh, bbase, part, E, Ec, NB);
    bucket_csr_kernel<<<NB, 256, 0, stream>>>(part, bbase, dinv, rowptr, edge, n);

    gemm_mfma_kernel<DIN, DH, false><<<nb_g, 256, 0, stream>>>(x, wt1, dinv, xw1, n);
    for (int s = 0; s < 4; ++s)
        agg_pass_kernel<true><<<nb_a, 256, 0, stream>>>(
            xw1 + (size_t)s * n * 32, rowptr, edge, dinv, b1 + 32 * s,
            h1 + (size_t)s * n * 32, n);
    gemm_mfma_kernel<DH, DOUT, true><<<nb_g, 256, 0, stream>>>(h1, wt2, dinv, xw2, n);
    for (int s = 0; s < 2; ++s)
        agg_pass_kernel<false><<<nb_a, 256, 0, stream>>>(
            xw2 + (size_t)s * n * 32, rowptr, edge, dinv, b2 + 32 * s,
            lg + (size_t)s * n * 32, n);
    lsm_kernel<<<nb_a, 256, 0, stream>>>(lg, out, n);
}